// Round 10
// baseline (361.471 us; speedup 1.0000x reference)
//
#include <hip/hip_runtime.h>
#include <hip/hip_bf16.h>
#include <stdint.h>

using u16 = unsigned short;

typedef __attribute__((ext_vector_type(8))) short bf16x8;
typedef __attribute__((ext_vector_type(4))) float f32x4;

typedef const __attribute__((address_space(1))) unsigned int* gas_t;
typedef __attribute__((address_space(3))) unsigned int* las_t;

__device__ inline void g2l16(const u16* g, u16* l) {
  __builtin_amdgcn_global_load_lds((gas_t)g, (las_t)l, 16, 0, 0);
}

__device__ inline u16 f2b(float x) {
  union { float f; uint32_t u; } v; v.f = x;
  uint32_t r = (v.u + 0x7FFFu + ((v.u >> 16) & 1u)) >> 16;
  return (u16)r;
}
__device__ inline float b2f(u16 b) {
  union { uint32_t u; float f; } v; v.u = ((uint32_t)b) << 16;
  return v.f;
}
__device__ inline float b2f_lo(uint32_t p) {
  union { uint32_t u; float f; } v; v.u = p << 16; return v.f;
}
__device__ inline float b2f_hi(uint32_t p) {
  union { uint32_t u; float f; } v; v.u = p & 0xFFFF0000u; return v.f;
}

__device__ inline void store_out(float* p, float v) { *p = v; }
__device__ inline void store_out(u16* p, float v) { *p = f2b(v); }

// ---------------------------------------------------------------------------
// Champion 128x128 GEMM core. BK=64, XOR-swizzled LDS (0 conflicts, proven).
// Computes acc only; epilogue is kernel-specific.
// ---------------------------------------------------------------------------
__device__ inline void gemm_core_128(const u16* __restrict__ A,
                                     const u16* __restrict__ Bt,
                                     int m0, int n0, int K,
                                     u16* As, u16* Bs, f32x4 (&acc)[4][4])
{
  const int tid  = threadIdx.x;
  const int wave = tid >> 6;
  const int lane = tid & 63;
  const int wm = wave >> 1, wn = wave & 1;
  const int lr = lane & 15;
  const int lq = lane >> 4;
  const int x7 = lr & 7;

  const int srow = tid >> 3;
  const int sgc  = (tid & 7) ^ (srow & 7);
  const u16* gA = A  + (size_t)(m0 + srow) * K + sgc * 8;
  const u16* gB = Bt + (size_t)(n0 + srow) * K + sgc * 8;
  u16* dstA = As + wave * 512;
  u16* dstB = Bs + wave * 512;

  #pragma unroll
  for (int i = 0; i < 4; ++i)
    #pragma unroll
    for (int j = 0; j < 4; ++j)
      acc[i][j] = (f32x4){0.f, 0.f, 0.f, 0.f};

  for (int k0 = 0; k0 < K; k0 += 64) {
    #pragma unroll
    for (int s = 0; s < 4; ++s) {
      g2l16(gA + (size_t)(s * 32) * K + k0, dstA + s * 2048);
      g2l16(gB + (size_t)(s * 32) * K + k0, dstB + s * 2048);
    }
    __syncthreads();

    #pragma unroll
    for (int ks = 0; ks < 2; ++ks) {
      const int pa = (ks * 4 + lq) ^ x7;
      bf16x8 af[4], bfr[4];
      #pragma unroll
      for (int im = 0; im < 4; ++im)
        af[im] = *(const bf16x8*)&As[(wm * 64 + im * 16 + lr) * 64 + pa * 8];
      #pragma unroll
      for (int in = 0; in < 4; ++in)
        bfr[in] = *(const bf16x8*)&Bs[(wn * 64 + in * 16 + lr) * 64 + pa * 8];

      #pragma unroll
      for (int im = 0; im < 4; ++im)
        #pragma unroll
        for (int in = 0; in < 4; ++in)
          acc[im][in] = __builtin_amdgcn_mfma_f32_16x16x32_bf16(
              af[im], bfr[in], acc[im][in], 0, 0, 0);
    }
    __syncthreads();
  }
}

// ---------------------------------------------------------------------------
// keys GEMM with FUSED score epilogue (proven R8) + last-block softmax:
// the final block to finish reads SCORE (agent-scoped loads; all writes to
// SCORE were device-scope atomics) and writes wmap -- kills the separate
// softmax dispatch.
// ---------------------------------------------------------------------------
__global__ __launch_bounds__(256)
void gemm_keys_score(const u16* __restrict__ WIb, const u16* __restrict__ IT,
                     const float* __restrict__ bim, u16* __restrict__ KEYS,
                     const u16* __restrict__ Qb, float* __restrict__ score,
                     unsigned* __restrict__ cnt, float* __restrict__ wmap)
{
  __shared__ u16 As[128 * 64];
  __shared__ u16 Bs[128 * 64];
  const int m0 = blockIdx.y * 128;
  const int n0 = blockIdx.x * 128;
  f32x4 acc[4][4];
  gemm_core_128(WIb, IT, m0, n0, 1024, As, Bs, acc);

  const int tid  = threadIdx.x;
  const int wave = tid >> 6;
  const int lane = tid & 63;
  const int wm = wave >> 1, wn = wave & 1;
  const int lr = lane & 15;
  const int lq = lane >> 4;
  const int h  = m0 >> 10;

  float sp[4] = {0.f, 0.f, 0.f, 0.f};
  #pragma unroll
  for (int im = 0; im < 4; ++im) {
    const int mbase = m0 + wm * 64 + im * 16 + lq * 4;
    #pragma unroll
    for (int in = 0; in < 4; ++in) {
      const int ncol = n0 + wn * 64 + in * 16 + lr;
      #pragma unroll
      for (int r = 0; r < 4; ++r) {
        const int m = mbase + r;
        const float v = acc[im][in][r] + bim[m];
        KEYS[(size_t)m * 4096 + ncol] = f2b(v);
        sp[in] = fmaf(v, b2f(Qb[(size_t)(m & 1023) * 4096 + ncol]), sp[in]);
      }
    }
  }
  #pragma unroll
  for (int in = 0; in < 4; ++in) {
    float v = sp[in];
    v += __shfl_down(v, 32);
    v += __shfl_down(v, 16);
    if (lane < 16)
      atomicAdd(&score[h * 4096 + n0 + wn * 64 + in * 16 + lane],
                v * 0.03125f);
  }

  // ---- last-block softmax over heads -> wmap ----
  __threadfence();                 // release my score atomics
  __shared__ unsigned lastf;
  if (tid == 0) {
    const unsigned prev = atomicAdd(cnt, 1u);
    lastf = (prev == 1023u) ? 1u : 0u;
  }
  __syncthreads();
  if (lastf) {
    __threadfence();               // acquire all blocks' score atomics
    const int nb = tid * 16;
    #pragma unroll 4
    for (int q = 0; q < 16; ++q) {
      const int n = nb + q;
      const float s0 = __hip_atomic_load(&score[n],
                          __ATOMIC_RELAXED, __HIP_MEMORY_SCOPE_AGENT);
      const float s1 = __hip_atomic_load(&score[4096 + n],
                          __ATOMIC_RELAXED, __HIP_MEMORY_SCOPE_AGENT);
      const float s2 = __hip_atomic_load(&score[8192 + n],
                          __ATOMIC_RELAXED, __HIP_MEMORY_SCOPE_AGENT);
      const float s3 = __hip_atomic_load(&score[12288 + n],
                          __ATOMIC_RELAXED, __HIP_MEMORY_SCOPE_AGENT);
      const float m = fmaxf(fmaxf(s0, s1), fmaxf(s2, s3));
      const float e0 = expf(s0 - m), e1 = expf(s1 - m);
      const float e2 = expf(s2 - m), e3 = expf(s3 - m);
      const float inv = 1.f / (e0 + e1 + e2 + e3);
      wmap[n] = e0 * inv; wmap[4096 + n] = e1 * inv;
      wmap[8192 + n] = e2 * inv; wmap[12288 + n] = e3 * inv;
    }
  }
}

// ---------------------------------------------------------------------------
// Plain 128x128 GEMM (dense 4x4 acc): used for Q = WL*P^T (bf16 out) and
// the final fp32 GEMM. Grid (32, 8) = 256 blocks each. (Proven in R5/R9.)
// ---------------------------------------------------------------------------
template<typename OutT>
__global__ __launch_bounds__(256)
void gemm_f(const u16* __restrict__ A, const u16* __restrict__ Bt,
            const float* __restrict__ bias, OutT* __restrict__ C)
{
  __shared__ u16 As[128 * 64];
  __shared__ u16 Bs[128 * 64];
  const int m0 = blockIdx.y * 128;
  const int n0 = blockIdx.x * 128;
  f32x4 acc[4][4];
  gemm_core_128(A, Bt, m0, n0, 1024, As, Bs, acc);

  const int tid  = threadIdx.x;
  const int wave = tid >> 6;
  const int lane = tid & 63;
  const int wm = wave >> 1, wn = wave & 1;
  const int lr = lane & 15;
  const int lq = lane >> 4;

  #pragma unroll
  for (int im = 0; im < 4; ++im) {
    const int mbase = m0 + wm * 64 + im * 16 + lq * 4;
    #pragma unroll
    for (int in = 0; in < 4; ++in) {
      const int ncol = n0 + wn * 64 + in * 16 + lr;
      #pragma unroll
      for (int r = 0; r < 4; ++r) {
        const int m = mbase + r;
        store_out(C + (size_t)m * 4096 + ncol, acc[im][in][r] + bias[m]);
      }
    }
  }
}

// ---------------------------------------------------------------------------
// Prep: P,I fp32->bf16 transposed + 3 weight casts + SCORE/counter zeroing.
// Champion 32x33 tile path. Grid 14353.
// ---------------------------------------------------------------------------
__global__ __launch_bounds__(256)
void prep(const float* __restrict__ P, u16* __restrict__ PT,
          const float* __restrict__ I, u16* __restrict__ IT,
          const float4* __restrict__ wim, const float4* __restrict__ wl,
          const float4* __restrict__ wf, ushort4* __restrict__ wimb,
          ushort4* __restrict__ wlb, ushort4* __restrict__ wfb,
          float* __restrict__ score)
{
  const int bid = blockIdx.x;
  if (bid < 8192) {
    const int z   = bid >> 12;          // 0: P, 1: I
    const int rem = bid & 4095;
    const int bx  = rem & 127;
    const int byy = rem >> 7;
    const float* in = z ? I : P;
    u16* out = z ? IT : PT;
    __shared__ u16 tile[32][33];
    const int c0 = bx * 32, r0 = byy * 32;
    const int tx = threadIdx.x & 31, ty = threadIdx.x >> 5;
    #pragma unroll
    for (int k = 0; k < 4; ++k)
      tile[ty + 8 * k][tx] = f2b(in[(size_t)(r0 + ty + 8 * k) * 4096 + c0 + tx]);
    __syncthreads();
    #pragma unroll
    for (int k = 0; k < 4; ++k)
      out[(size_t)(c0 + ty + 8 * k) * 1024 + r0 + tx] = tile[tx][ty + 8 * k];
  } else if (bid < 14336) {
    int i = (bid - 8192) * 256 + threadIdx.x;
    const float4* src; ushort4* dst;
    if (i < 1048576)      { src = wim; dst = wimb; }
    else if (i < 1310720) { src = wl;  dst = wlb;  i -= 1048576; }
    else                  { src = wf;  dst = wfb;  i -= 1310720; }
    const float4 v = src[i];
    ushort4 o;
    o.x = f2b(v.x); o.y = f2b(v.y); o.z = f2b(v.z); o.w = f2b(v.w);
    dst[i] = o;
  } else {
    // 17 blocks x 256 threads x 4 floats: zero SCORE (16384) + counter (+1KB)
    const int i = (bid - 14336) * 1024 + threadIdx.x * 4;
    *(float4*)&score[i] = (float4){0.f, 0.f, 0.f, 0.f};
  }
}

// z = sum_h w[h][n]*keys[h][c][n]; t = z + Q; LayerNorm over n; bf16 out.
__global__ __launch_bounds__(256)
void z_ln(const u16* __restrict__ keys, const u16* __restrict__ Qb,
          const float* __restrict__ w, const float* __restrict__ g,
          const float* __restrict__ bb, u16* __restrict__ fused)
{
  const int c  = blockIdx.x;
  const int tx = threadIdx.x;
  float t[16];
  float s = 0.f, s2 = 0.f;
  #pragma unroll
  for (int j = 0; j < 2; ++j) {
    const int n = tx * 8 + j * 2048;
    const uint4 qv = *(const uint4*)&Qb[(size_t)c * 4096 + n];
    float z[8] = {0.f,0.f,0.f,0.f,0.f,0.f,0.f,0.f};
    #pragma unroll
    for (int h = 0; h < 4; ++h) {
      const uint4 kv = *(const uint4*)&keys[((size_t)((h << 10) + c)) * 4096 + n];
      const float4 w0 = *(const float4*)&w[h * 4096 + n];
      const float4 w1 = *(const float4*)&w[h * 4096 + n + 4];
      z[0] = fmaf(w0.x, b2f_lo(kv.x), z[0]);
      z[1] = fmaf(w0.y, b2f_hi(kv.x), z[1]);
      z[2] = fmaf(w0.z, b2f_lo(kv.y), z[2]);
      z[3] = fmaf(w0.w, b2f_hi(kv.y), z[3]);
      z[4] = fmaf(w1.x, b2f_lo(kv.z), z[4]);
      z[5] = fmaf(w1.y, b2f_hi(kv.z), z[5]);
      z[6] = fmaf(w1.z, b2f_lo(kv.w), z[6]);
      z[7] = fmaf(w1.w, b2f_hi(kv.w), z[7]);
    }
    const uint32_t qs[4] = {qv.x, qv.y, qv.z, qv.w};
    #pragma unroll
    for (int e = 0; e < 4; ++e) {
      const float v0 = z[2 * e]     + b2f_lo(qs[e]);
      const float v1 = z[2 * e + 1] + b2f_hi(qs[e]);
      t[8 * j + 2 * e]     = v0;
      t[8 * j + 2 * e + 1] = v1;
      s += v0 + v1;
      s2 = fmaf(v0, v0, fmaf(v1, v1, s2));
    }
  }
  #pragma unroll
  for (int o = 32; o > 0; o >>= 1) {
    s  += __shfl_down(s, o);
    s2 += __shfl_down(s2, o);
  }
  __shared__ float rbuf[8];
  const int wave = tx >> 6, lane = tx & 63;
  if (lane == 0) { rbuf[wave] = s; rbuf[4 + wave] = s2; }
  __syncthreads();
  s  = rbuf[0] + rbuf[1] + rbuf[2] + rbuf[3];
  s2 = rbuf[4] + rbuf[5] + rbuf[6] + rbuf[7];
  const float mu  = s * (1.f / 4096.f);
  const float var = s2 * (1.f / 4096.f) - mu * mu;
  const float rs  = rsqrtf(var + 1e-5f);
  #pragma unroll
  for (int j = 0; j < 2; ++j) {
    const int n = tx * 8 + j * 2048;
    #pragma unroll
    for (int q4 = 0; q4 < 2; ++q4) {
      const float4 gv = *(const float4*)&g[n + 4 * q4];
      const float4 bv = *(const float4*)&bb[n + 4 * q4];
      ushort4 o;
      o.x = f2b((t[8 * j + 4 * q4]     - mu) * rs * gv.x + bv.x);
      o.y = f2b((t[8 * j + 4 * q4 + 1] - mu) * rs * gv.y + bv.y);
      o.z = f2b((t[8 * j + 4 * q4 + 2] - mu) * rs * gv.z + bv.z);
      o.w = f2b((t[8 * j + 4 * q4 + 3] - mu) * rs * gv.w + bv.w);
      *(ushort4*)&fused[(size_t)c * 4096 + n + 4 * q4] = o;
    }
  }
}

// bf16 [R x C] -> bf16 [C x R]  (champion 32x33)
__global__ __launch_bounds__(256)
void transpose_u16(const u16* __restrict__ in, u16* __restrict__ out,
                   int R, int C)
{
  __shared__ u16 tile[32][33];
  const int c0 = blockIdx.x * 32, r0 = blockIdx.y * 32;
  const int tx = threadIdx.x & 31, ty = threadIdx.x >> 5;
  #pragma unroll
  for (int k = 0; k < 4; ++k)
    tile[ty + 8 * k][tx] = in[(size_t)(r0 + ty + 8 * k) * C + c0 + tx];
  __syncthreads();
  #pragma unroll
  for (int k = 0; k < 4; ++k)
    out[(size_t)(c0 + ty + 8 * k) * R + r0 + tx] = tile[tx][ty + 8 * k];
}

extern "C" void kernel_launch(void* const* d_in, const int* in_sizes, int n_in,
                              void* d_out, int out_size, void* d_ws, size_t ws_size,
                              hipStream_t stream)
{
  const float* P   = (const float*)d_in[0];
  const float* I   = (const float*)d_in[1];
  const float* Wim = (const float*)d_in[2];
  const float* bim = (const float*)d_in[3];
  const float* WL  = (const float*)d_in[4];
  const float* bL  = (const float*)d_in[5];
  const float* lng = (const float*)d_in[6];
  const float* lnb = (const float*)d_in[7];
  const float* Wf  = (const float*)d_in[8];
  const float* bf_ = (const float*)d_in[9];
  float* out = (float*)d_out;

  char* ws = (char*)d_ws;
  u16*   PT     = (u16*)(ws + 0);                      //  8 MB [4096 x 1024]
  u16*   IT     = (u16*)(ws + (size_t)8  * 1048576);   //  8 MB
  u16*   WLb    = (u16*)(ws + (size_t)16 * 1048576);   //  2 MB
  u16*   WIb    = (u16*)(ws + (size_t)18 * 1048576);   //  8 MB
  u16*   WFb    = (u16*)(ws + (size_t)26 * 1048576);   //  2 MB
  u16*   Qb     = (u16*)(ws + (size_t)28 * 1048576);   //  8 MB [1024 x 4096]
  u16*   KEYS   = (u16*)(ws + (size_t)36 * 1048576);   // 32 MB [4096 x 4096]
  float* SCORE  = (float*)(ws + (size_t)68 * 1048576); // 64 KB [4 x 4096]
  unsigned* CNT = (unsigned*)(ws + (size_t)68 * 1048576 + 65536); // in zeroed region
  u16*   FUSED  = (u16*)(ws + (size_t)70 * 1048576);   //  8 MB [1024 x 4096]
  u16*   FUSEDT = (u16*)(ws + (size_t)78 * 1048576);   //  8 MB [4096 x 1024]

  const dim3 b256(256);

  // input casts/transposes + SCORE/counter zeroing, one dispatch
  prep<<<14353, b256, 0, stream>>>(P, PT, I, IT,
                                   (const float4*)Wim, (const float4*)WL,
                                   (const float4*)Wf, (ushort4*)WIb,
                                   (ushort4*)WLb, (ushort4*)WFb, SCORE);

  // Q = W_L * P^T  [1024 x 4096] bf16 (dense 128^2 tile, 256 blocks)
  gemm_f<u16><<<dim3(32, 8), b256, 0, stream>>>(WLb, PT, bL, Qb);

  // keys [4096x4096] bf16 + FUSED score + last-block softmax -> wmap
  float* wmap = out + (size_t)1024 * 4096;
  gemm_keys_score<<<dim3(32, 32), b256, 0, stream>>>(WIb, IT, bim, KEYS,
                                                     Qb, SCORE, CNT, wmap);

  // z + residual + LayerNorm -> bf16, then transpose for final GEMM
  z_ln<<<1024, b256, 0, stream>>>(KEYS, Qb, wmap, lng, lnb, FUSED);
  transpose_u16<<<dim3(128, 32), b256, 0, stream>>>(FUSED, FUSEDT, 1024, 4096);

  // out = W_f * fused + b_f  [1024 x 4096] fp32 (dense 128^2 tile)
  gemm_f<float><<<dim3(32, 8), b256, 0, stream>>>(WFb, FUSEDT, bf_, out);
}

// Round 11
// 210.582 us; speedup vs baseline: 1.7165x; 1.7165x over previous
//
#include <hip/hip_runtime.h>
#include <hip/hip_bf16.h>
#include <stdint.h>

using u16 = unsigned short;

typedef __attribute__((ext_vector_type(8))) short bf16x8;
typedef __attribute__((ext_vector_type(4))) float f32x4;

typedef const __attribute__((address_space(1))) unsigned int* gas_t;
typedef __attribute__((address_space(3))) unsigned int* las_t;

__device__ inline void g2l16(const u16* g, u16* l) {
  __builtin_amdgcn_global_load_lds((gas_t)g, (las_t)l, 16, 0, 0);
}

__device__ inline u16 f2b(float x) {
  union { float f; uint32_t u; } v; v.f = x;
  uint32_t r = (v.u + 0x7FFFu + ((v.u >> 16) & 1u)) >> 16;
  return (u16)r;
}
__device__ inline float b2f(u16 b) {
  union { uint32_t u; float f; } v; v.u = ((uint32_t)b) << 16;
  return v.f;
}
__device__ inline float b2f_lo(uint32_t p) {
  union { uint32_t u; float f; } v; v.u = p << 16; return v.f;
}
__device__ inline float b2f_hi(uint32_t p) {
  union { uint32_t u; float f; } v; v.u = p & 0xFFFF0000u; return v.f;
}

__device__ inline void store_out(float* p, float v) { *p = v; }
__device__ inline void store_out(u16* p, float v) { *p = f2b(v); }

// ---------------------------------------------------------------------------
// Champion 128x128 GEMM core. BK=64, XOR-swizzled LDS (0 conflicts, proven).
// Computes acc only; epilogue is kernel-specific.
// NOTE (session rule): no device-scope fences anywhere near this loop --
// R10 showed one __threadfence per block costs 4x via L2 invalidation.
// ---------------------------------------------------------------------------
__device__ inline void gemm_core_128(const u16* __restrict__ A,
                                     const u16* __restrict__ Bt,
                                     int m0, int n0, int K,
                                     u16* As, u16* Bs, f32x4 (&acc)[4][4])
{
  const int tid  = threadIdx.x;
  const int wave = tid >> 6;
  const int lane = tid & 63;
  const int wm = wave >> 1, wn = wave & 1;
  const int lr = lane & 15;
  const int lq = lane >> 4;
  const int x7 = lr & 7;

  const int srow = tid >> 3;
  const int sgc  = (tid & 7) ^ (srow & 7);
  const u16* gA = A  + (size_t)(m0 + srow) * K + sgc * 8;
  const u16* gB = Bt + (size_t)(n0 + srow) * K + sgc * 8;
  u16* dstA = As + wave * 512;
  u16* dstB = Bs + wave * 512;

  #pragma unroll
  for (int i = 0; i < 4; ++i)
    #pragma unroll
    for (int j = 0; j < 4; ++j)
      acc[i][j] = (f32x4){0.f, 0.f, 0.f, 0.f};

  for (int k0 = 0; k0 < K; k0 += 64) {
    #pragma unroll
    for (int s = 0; s < 4; ++s) {
      g2l16(gA + (size_t)(s * 32) * K + k0, dstA + s * 2048);
      g2l16(gB + (size_t)(s * 32) * K + k0, dstB + s * 2048);
    }
    __syncthreads();

    #pragma unroll
    for (int ks = 0; ks < 2; ++ks) {
      const int pa = (ks * 4 + lq) ^ x7;
      bf16x8 af[4], bfr[4];
      #pragma unroll
      for (int im = 0; im < 4; ++im)
        af[im] = *(const bf16x8*)&As[(wm * 64 + im * 16 + lr) * 64 + pa * 8];
      #pragma unroll
      for (int in = 0; in < 4; ++in)
        bfr[in] = *(const bf16x8*)&Bs[(wn * 64 + in * 16 + lr) * 64 + pa * 8];

      #pragma unroll
      for (int im = 0; im < 4; ++im)
        #pragma unroll
        for (int in = 0; in < 4; ++in)
          acc[im][in] = __builtin_amdgcn_mfma_f32_16x16x32_bf16(
              af[im], bfr[in], acc[im][in], 0, 0, 0);
    }
    __syncthreads();
  }
}

// ---------------------------------------------------------------------------
// keys GEMM with FUSED score epilogue (proven R8, 49-51 us). Grid (32, 32).
// ---------------------------------------------------------------------------
__global__ __launch_bounds__(256)
void gemm_keys_score(const u16* __restrict__ WIb, const u16* __restrict__ IT,
                     const float* __restrict__ bim, u16* __restrict__ KEYS,
                     const u16* __restrict__ Qb, float* __restrict__ score)
{
  __shared__ u16 As[128 * 64];
  __shared__ u16 Bs[128 * 64];
  const int m0 = blockIdx.y * 128;
  const int n0 = blockIdx.x * 128;
  f32x4 acc[4][4];
  gemm_core_128(WIb, IT, m0, n0, 1024, As, Bs, acc);

  const int tid  = threadIdx.x;
  const int wave = tid >> 6;
  const int lane = tid & 63;
  const int wm = wave >> 1, wn = wave & 1;
  const int lr = lane & 15;
  const int lq = lane >> 4;
  const int h  = m0 >> 10;

  float sp[4] = {0.f, 0.f, 0.f, 0.f};
  #pragma unroll
  for (int im = 0; im < 4; ++im) {
    const int mbase = m0 + wm * 64 + im * 16 + lq * 4;
    #pragma unroll
    for (int in = 0; in < 4; ++in) {
      const int ncol = n0 + wn * 64 + in * 16 + lr;
      #pragma unroll
      for (int r = 0; r < 4; ++r) {
        const int m = mbase + r;
        const float v = acc[im][in][r] + bim[m];
        KEYS[(size_t)m * 4096 + ncol] = f2b(v);
        sp[in] = fmaf(v, b2f(Qb[(size_t)(m & 1023) * 4096 + ncol]), sp[in]);
      }
    }
  }
  #pragma unroll
  for (int in = 0; in < 4; ++in) {
    float v = sp[in];
    v += __shfl_down(v, 32);
    v += __shfl_down(v, 16);
    if (lane < 16)
      atomicAdd(&score[h * 4096 + n0 + wn * 64 + in * 16 + lane],
                v * 0.03125f);
  }
}

// ---------------------------------------------------------------------------
// Plain 128x128 GEMM (dense 4x4 acc): used for Q = WL*P^T (bf16 out) and
// the final fp32 GEMM. Grid (32, 8) = 256 blocks each. (Proven R5/R9.)
// ---------------------------------------------------------------------------
template<typename OutT>
__global__ __launch_bounds__(256)
void gemm_f(const u16* __restrict__ A, const u16* __restrict__ Bt,
            const float* __restrict__ bias, OutT* __restrict__ C)
{
  __shared__ u16 As[128 * 64];
  __shared__ u16 Bs[128 * 64];
  const int m0 = blockIdx.y * 128;
  const int n0 = blockIdx.x * 128;
  f32x4 acc[4][4];
  gemm_core_128(A, Bt, m0, n0, 1024, As, Bs, acc);

  const int tid  = threadIdx.x;
  const int wave = tid >> 6;
  const int lane = tid & 63;
  const int wm = wave >> 1, wn = wave & 1;
  const int lr = lane & 15;
  const int lq = lane >> 4;

  #pragma unroll
  for (int im = 0; im < 4; ++im) {
    const int mbase = m0 + wm * 64 + im * 16 + lq * 4;
    #pragma unroll
    for (int in = 0; in < 4; ++in) {
      const int ncol = n0 + wn * 64 + in * 16 + lr;
      #pragma unroll
      for (int r = 0; r < 4; ++r) {
        const int m = mbase + r;
        store_out(C + (size_t)m * 4096 + ncol, acc[im][in][r] + bias[m]);
      }
    }
  }
}

// ---------------------------------------------------------------------------
// Prep: P,I fp32->bf16 transposed + 3 weight casts + SCORE zeroing
// (proven R9). Champion 32x33 tile path. Grid 14352.
// ---------------------------------------------------------------------------
__global__ __launch_bounds__(256)
void prep(const float* __restrict__ P, u16* __restrict__ PT,
          const float* __restrict__ I, u16* __restrict__ IT,
          const float4* __restrict__ wim, const float4* __restrict__ wl,
          const float4* __restrict__ wf, ushort4* __restrict__ wimb,
          ushort4* __restrict__ wlb, ushort4* __restrict__ wfb,
          float* __restrict__ score)
{
  const int bid = blockIdx.x;
  if (bid < 8192) {
    const int z   = bid >> 12;          // 0: P, 1: I
    const int rem = bid & 4095;
    const int bx  = rem & 127;
    const int byy = rem >> 7;
    const float* in = z ? I : P;
    u16* out = z ? IT : PT;
    __shared__ u16 tile[32][33];
    const int c0 = bx * 32, r0 = byy * 32;
    const int tx = threadIdx.x & 31, ty = threadIdx.x >> 5;
    #pragma unroll
    for (int k = 0; k < 4; ++k)
      tile[ty + 8 * k][tx] = f2b(in[(size_t)(r0 + ty + 8 * k) * 4096 + c0 + tx]);
    __syncthreads();
    #pragma unroll
    for (int k = 0; k < 4; ++k)
      out[(size_t)(c0 + ty + 8 * k) * 1024 + r0 + tx] = tile[tx][ty + 8 * k];
  } else if (bid < 14336) {
    int i = (bid - 8192) * 256 + threadIdx.x;
    const float4* src; ushort4* dst;
    if (i < 1048576)      { src = wim; dst = wimb; }
    else if (i < 1310720) { src = wl;  dst = wlb;  i -= 1048576; }
    else                  { src = wf;  dst = wfb;  i -= 1310720; }
    const float4 v = src[i];
    ushort4 o;
    o.x = f2b(v.x); o.y = f2b(v.y); o.z = f2b(v.z); o.w = f2b(v.w);
    dst[i] = o;
  } else {
    // 16 blocks x 256 threads x 4 floats = 16384 = 4*4096 (SCORE zero)
    const int i = (bid - 14336) * 1024 + threadIdx.x * 4;
    *(float4*)&score[i] = (float4){0.f, 0.f, 0.f, 0.f};
  }
}

// bf16 [R x C] -> bf16 [C x R]  (champion 32x33)
__global__ __launch_bounds__(256)
void transpose_u16(const u16* __restrict__ in, u16* __restrict__ out,
                   int R, int C)
{
  __shared__ u16 tile[32][33];
  const int c0 = blockIdx.x * 32, r0 = blockIdx.y * 32;
  const int tx = threadIdx.x & 31, ty = threadIdx.x >> 5;
  #pragma unroll
  for (int k = 0; k < 4; ++k)
    tile[ty + 8 * k][tx] = in[(size_t)(r0 + ty + 8 * k) * C + c0 + tx];
  __syncthreads();
  #pragma unroll
  for (int k = 0; k < 4; ++k)
    out[(size_t)(c0 + ty + 8 * k) * R + r0 + tx] = tile[tx][ty + 8 * k];
}

// softmax over 4 heads -> weightmap (champion version)
__global__ __launch_bounds__(256)
void softmax_h(const float* __restrict__ score, float* __restrict__ wmap)
{
  const int n = blockIdx.x * 256 + threadIdx.x;
  const float s0 = score[n], s1 = score[4096 + n];
  const float s2 = score[8192 + n], s3 = score[12288 + n];
  const float m = fmaxf(fmaxf(s0, s1), fmaxf(s2, s3));
  const float e0 = expf(s0 - m), e1 = expf(s1 - m);
  const float e2 = expf(s2 - m), e3 = expf(s3 - m);
  const float inv = 1.f / (e0 + e1 + e2 + e3);
  wmap[n] = e0 * inv; wmap[4096 + n] = e1 * inv;
  wmap[8192 + n] = e2 * inv; wmap[12288 + n] = e3 * inv;
}

// z = sum_h w[h][n]*keys[h][c][n]; t = z + Q; LayerNorm over n; bf16 out.
__global__ __launch_bounds__(256)
void z_ln(const u16* __restrict__ keys, const u16* __restrict__ Qb,
          const float* __restrict__ w, const float* __restrict__ g,
          const float* __restrict__ bb, u16* __restrict__ fused)
{
  const int c  = blockIdx.x;
  const int tx = threadIdx.x;
  float t[16];
  float s = 0.f, s2 = 0.f;
  #pragma unroll
  for (int j = 0; j < 2; ++j) {
    const int n = tx * 8 + j * 2048;
    const uint4 qv = *(const uint4*)&Qb[(size_t)c * 4096 + n];
    float z[8] = {0.f,0.f,0.f,0.f,0.f,0.f,0.f,0.f};
    #pragma unroll
    for (int h = 0; h < 4; ++h) {
      const uint4 kv = *(const uint4*)&keys[((size_t)((h << 10) + c)) * 4096 + n];
      const float4 w0 = *(const float4*)&w[h * 4096 + n];
      const float4 w1 = *(const float4*)&w[h * 4096 + n + 4];
      z[0] = fmaf(w0.x, b2f_lo(kv.x), z[0]);
      z[1] = fmaf(w0.y, b2f_hi(kv.x), z[1]);
      z[2] = fmaf(w0.z, b2f_lo(kv.y), z[2]);
      z[3] = fmaf(w0.w, b2f_hi(kv.y), z[3]);
      z[4] = fmaf(w1.x, b2f_lo(kv.z), z[4]);
      z[5] = fmaf(w1.y, b2f_hi(kv.z), z[5]);
      z[6] = fmaf(w1.z, b2f_lo(kv.w), z[6]);
      z[7] = fmaf(w1.w, b2f_hi(kv.w), z[7]);
    }
    const uint32_t qs[4] = {qv.x, qv.y, qv.z, qv.w};
    #pragma unroll
    for (int e = 0; e < 4; ++e) {
      const float v0 = z[2 * e]     + b2f_lo(qs[e]);
      const float v1 = z[2 * e + 1] + b2f_hi(qs[e]);
      t[8 * j + 2 * e]     = v0;
      t[8 * j + 2 * e + 1] = v1;
      s += v0 + v1;
      s2 = fmaf(v0, v0, fmaf(v1, v1, s2));
    }
  }
  #pragma unroll
  for (int o = 32; o > 0; o >>= 1) {
    s  += __shfl_down(s, o);
    s2 += __shfl_down(s2, o);
  }
  __shared__ float rbuf[8];
  const int wave = tx >> 6, lane = tx & 63;
  if (lane == 0) { rbuf[wave] = s; rbuf[4 + wave] = s2; }
  __syncthreads();
  s  = rbuf[0] + rbuf[1] + rbuf[2] + rbuf[3];
  s2 = rbuf[4] + rbuf[5] + rbuf[6] + rbuf[7];
  const float mu  = s * (1.f / 4096.f);
  const float var = s2 * (1.f / 4096.f) - mu * mu;
  const float rs  = rsqrtf(var + 1e-5f);
  #pragma unroll
  for (int j = 0; j < 2; ++j) {
    const int n = tx * 8 + j * 2048;
    #pragma unroll
    for (int q4 = 0; q4 < 2; ++q4) {
      const float4 gv = *(const float4*)&g[n + 4 * q4];
      const float4 bv = *(const float4*)&bb[n + 4 * q4];
      ushort4 o;
      o.x = f2b((t[8 * j + 4 * q4]     - mu) * rs * gv.x + bv.x);
      o.y = f2b((t[8 * j + 4 * q4 + 1] - mu) * rs * gv.y + bv.y);
      o.z = f2b((t[8 * j + 4 * q4 + 2] - mu) * rs * gv.z + bv.z);
      o.w = f2b((t[8 * j + 4 * q4 + 3] - mu) * rs * gv.w + bv.w);
      *(ushort4*)&fused[(size_t)c * 4096 + n + 4 * q4] = o;
    }
  }
}

extern "C" void kernel_launch(void* const* d_in, const int* in_sizes, int n_in,
                              void* d_out, int out_size, void* d_ws, size_t ws_size,
                              hipStream_t stream)
{
  const float* P   = (const float*)d_in[0];
  const float* I   = (const float*)d_in[1];
  const float* Wim = (const float*)d_in[2];
  const float* bim = (const float*)d_in[3];
  const float* WL  = (const float*)d_in[4];
  const float* bL  = (const float*)d_in[5];
  const float* lng = (const float*)d_in[6];
  const float* lnb = (const float*)d_in[7];
  const float* Wf  = (const float*)d_in[8];
  const float* bf_ = (const float*)d_in[9];
  float* out = (float*)d_out;

  char* ws = (char*)d_ws;
  u16*   PT     = (u16*)(ws + 0);                      //  8 MB [4096 x 1024]
  u16*   IT     = (u16*)(ws + (size_t)8  * 1048576);   //  8 MB
  u16*   WLb    = (u16*)(ws + (size_t)16 * 1048576);   //  2 MB
  u16*   WIb    = (u16*)(ws + (size_t)18 * 1048576);   //  8 MB
  u16*   WFb    = (u16*)(ws + (size_t)26 * 1048576);   //  2 MB
  u16*   Qb     = (u16*)(ws + (size_t)28 * 1048576);   //  8 MB [1024 x 4096]
  u16*   KEYS   = (u16*)(ws + (size_t)36 * 1048576);   // 32 MB [4096 x 4096]
  float* SCORE  = (float*)(ws + (size_t)68 * 1048576); // 64 KB [4 x 4096]
  u16*   FUSED  = (u16*)(ws + (size_t)70 * 1048576);   //  8 MB [1024 x 4096]
  u16*   FUSEDT = (u16*)(ws + (size_t)78 * 1048576);   //  8 MB [4096 x 1024]

  const dim3 b256(256);

  // input casts/transposes + SCORE zeroing, one dispatch (14352 blocks)
  prep<<<14352, b256, 0, stream>>>(P, PT, I, IT,
                                   (const float4*)Wim, (const float4*)WL,
                                   (const float4*)Wf, (ushort4*)WIb,
                                   (ushort4*)WLb, (ushort4*)WFb, SCORE);

  // Q = W_L * P^T  [1024 x 4096] bf16 (dense 128^2 tile, 256 blocks)
  gemm_f<u16><<<dim3(32, 8), b256, 0, stream>>>(WLb, PT, bL, Qb);

  // keys [4096x4096] bf16 with FUSED score accumulation (1024 blocks)
  gemm_keys_score<<<dim3(32, 32), b256, 0, stream>>>(WIb, IT, bim, KEYS,
                                                     Qb, SCORE);

  // softmax over heads -> weightmap
  float* wmap = out + (size_t)1024 * 4096;
  softmax_h<<<16, b256, 0, stream>>>(SCORE, wmap);

  // z + residual + LayerNorm -> bf16, then transpose for final GEMM
  z_ln<<<1024, b256, 0, stream>>>(KEYS, Qb, wmap, lng, lnb, FUSED);
  transpose_u16<<<dim3(128, 32), b256, 0, stream>>>(FUSED, FUSEDT, 1024, 4096);

  // out = W_f * fused + b_f  [1024 x 4096] fp32 (dense 128^2 tile)
  gemm_f<float><<<dim3(32, 8), b256, 0, stream>>>(WFb, FUSEDT, bf_, out);
}

// Round 12
// 206.736 us; speedup vs baseline: 1.7485x; 1.0186x over previous
//
#include <hip/hip_runtime.h>
#include <hip/hip_bf16.h>
#include <stdint.h>

using u16 = unsigned short;

typedef __attribute__((ext_vector_type(8))) short bf16x8;
typedef __attribute__((ext_vector_type(4))) float f32x4;

typedef const __attribute__((address_space(1))) unsigned int* gas_t;
typedef __attribute__((address_space(3))) unsigned int* las_t;

__device__ inline void g2l16(const u16* g, u16* l) {
  __builtin_amdgcn_global_load_lds((gas_t)g, (las_t)l, 16, 0, 0);
}

__device__ inline u16 f2b(float x) {
  union { float f; uint32_t u; } v; v.f = x;
  uint32_t r = (v.u + 0x7FFFu + ((v.u >> 16) & 1u)) >> 16;
  return (u16)r;
}
__device__ inline float b2f(u16 b) {
  union { uint32_t u; float f; } v; v.u = ((uint32_t)b) << 16;
  return v.f;
}
__device__ inline float b2f_lo(uint32_t p) {
  union { uint32_t u; float f; } v; v.u = p << 16; return v.f;
}
__device__ inline float b2f_hi(uint32_t p) {
  union { uint32_t u; float f; } v; v.u = p & 0xFFFF0000u; return v.f;
}

__device__ inline void store_out(float* p, float v) { *p = v; }
__device__ inline void store_out(u16* p, float v) { *p = f2b(v); }

// ---------------------------------------------------------------------------
// Champion 128x128 GEMM core. BK=64, XOR-swizzled LDS (0 conflicts, proven).
// NOTE (session rule): no device-scope fences anywhere near this loop --
// R10 showed one __threadfence per block costs 4x via L2 invalidation.
// ---------------------------------------------------------------------------
__device__ inline void gemm_core_128(const u16* __restrict__ A,
                                     const u16* __restrict__ Bt,
                                     int m0, int n0, int K,
                                     u16* As, u16* Bs, f32x4 (&acc)[4][4])
{
  const int tid  = threadIdx.x;
  const int wave = tid >> 6;
  const int lane = tid & 63;
  const int wm = wave >> 1, wn = wave & 1;
  const int lr = lane & 15;
  const int lq = lane >> 4;
  const int x7 = lr & 7;

  const int srow = tid >> 3;
  const int sgc  = (tid & 7) ^ (srow & 7);
  const u16* gA = A  + (size_t)(m0 + srow) * K + sgc * 8;
  const u16* gB = Bt + (size_t)(n0 + srow) * K + sgc * 8;
  u16* dstA = As + wave * 512;
  u16* dstB = Bs + wave * 512;

  #pragma unroll
  for (int i = 0; i < 4; ++i)
    #pragma unroll
    for (int j = 0; j < 4; ++j)
      acc[i][j] = (f32x4){0.f, 0.f, 0.f, 0.f};

  for (int k0 = 0; k0 < K; k0 += 64) {
    #pragma unroll
    for (int s = 0; s < 4; ++s) {
      g2l16(gA + (size_t)(s * 32) * K + k0, dstA + s * 2048);
      g2l16(gB + (size_t)(s * 32) * K + k0, dstB + s * 2048);
    }
    __syncthreads();

    #pragma unroll
    for (int ks = 0; ks < 2; ++ks) {
      const int pa = (ks * 4 + lq) ^ x7;
      bf16x8 af[4], bfr[4];
      #pragma unroll
      for (int im = 0; im < 4; ++im)
        af[im] = *(const bf16x8*)&As[(wm * 64 + im * 16 + lr) * 64 + pa * 8];
      #pragma unroll
      for (int in = 0; in < 4; ++in)
        bfr[in] = *(const bf16x8*)&Bs[(wn * 64 + in * 16 + lr) * 64 + pa * 8];

      #pragma unroll
      for (int im = 0; im < 4; ++im)
        #pragma unroll
        for (int in = 0; in < 4; ++in)
          acc[im][in] = __builtin_amdgcn_mfma_f32_16x16x32_bf16(
              af[im], bfr[in], acc[im][in], 0, 0, 0);
    }
    __syncthreads();
  }
}

// ---------------------------------------------------------------------------
// keys GEMM with FUSED score epilogue (proven R8, 49-51 us). Grid (32, 32).
// ---------------------------------------------------------------------------
__global__ __launch_bounds__(256)
void gemm_keys_score(const u16* __restrict__ WIb, const u16* __restrict__ IT,
                     const float* __restrict__ bim, u16* __restrict__ KEYS,
                     const u16* __restrict__ Qb, float* __restrict__ score)
{
  __shared__ u16 As[128 * 64];
  __shared__ u16 Bs[128 * 64];
  const int m0 = blockIdx.y * 128;
  const int n0 = blockIdx.x * 128;
  f32x4 acc[4][4];
  gemm_core_128(WIb, IT, m0, n0, 1024, As, Bs, acc);

  const int tid  = threadIdx.x;
  const int wave = tid >> 6;
  const int lane = tid & 63;
  const int wm = wave >> 1, wn = wave & 1;
  const int lr = lane & 15;
  const int lq = lane >> 4;
  const int h  = m0 >> 10;

  float sp[4] = {0.f, 0.f, 0.f, 0.f};
  #pragma unroll
  for (int im = 0; im < 4; ++im) {
    const int mbase = m0 + wm * 64 + im * 16 + lq * 4;
    #pragma unroll
    for (int in = 0; in < 4; ++in) {
      const int ncol = n0 + wn * 64 + in * 16 + lr;
      #pragma unroll
      for (int r = 0; r < 4; ++r) {
        const int m = mbase + r;
        const float v = acc[im][in][r] + bim[m];
        KEYS[(size_t)m * 4096 + ncol] = f2b(v);
        sp[in] = fmaf(v, b2f(Qb[(size_t)(m & 1023) * 4096 + ncol]), sp[in]);
      }
    }
  }
  #pragma unroll
  for (int in = 0; in < 4; ++in) {
    float v = sp[in];
    v += __shfl_down(v, 32);
    v += __shfl_down(v, 16);
    if (lane < 16)
      atomicAdd(&score[h * 4096 + n0 + wn * 64 + in * 16 + lane],
                v * 0.03125f);
  }
}

// ---------------------------------------------------------------------------
// 64x128 tile GEMM (R8 proven): Q = WL*P^T (bf16) and final fp32 GEMM.
// Grid (32,16) = 512 blocks = 2 blocks/CU (inter-block overlap).
// ---------------------------------------------------------------------------
template<typename OutT>
__global__ __launch_bounds__(256)
void gemm_bt_64(const u16* __restrict__ A, const u16* __restrict__ Bt,
                const float* __restrict__ bias, OutT* __restrict__ C,
                int M, int N, int K)
{
  __shared__ u16 As[64 * 64];
  __shared__ u16 Bs[128 * 64];

  const int tid  = threadIdx.x;
  const int wave = tid >> 6;
  const int lane = tid & 63;
  const int lr = lane & 15;
  const int lq = lane >> 4;
  const int x7 = lr & 7;

  const int m0 = blockIdx.y * 64;
  const int n0 = blockIdx.x * 128;

  const int srow = tid >> 3;
  const int sgc  = (tid & 7) ^ (srow & 7);
  const u16* gA = A  + (size_t)(m0 + srow) * K + sgc * 8;
  const u16* gB = Bt + (size_t)(n0 + srow) * K + sgc * 8;
  u16* dstA = As + wave * 512;
  u16* dstB = Bs + wave * 512;

  f32x4 acc[4][2];
  #pragma unroll
  for (int i = 0; i < 4; ++i)
    #pragma unroll
    for (int j = 0; j < 2; ++j)
      acc[i][j] = (f32x4){0.f, 0.f, 0.f, 0.f};

  for (int k0 = 0; k0 < K; k0 += 64) {
    #pragma unroll
    for (int s = 0; s < 2; ++s)
      g2l16(gA + (size_t)(s * 32) * K + k0, dstA + s * 2048);
    #pragma unroll
    for (int s = 0; s < 4; ++s)
      g2l16(gB + (size_t)(s * 32) * K + k0, dstB + s * 2048);
    __syncthreads();

    #pragma unroll
    for (int ks = 0; ks < 2; ++ks) {
      const int pa = (ks * 4 + lq) ^ x7;
      bf16x8 af[4], bfr[2];
      #pragma unroll
      for (int im = 0; im < 4; ++im)
        af[im] = *(const bf16x8*)&As[(im * 16 + lr) * 64 + pa * 8];
      #pragma unroll
      for (int in = 0; in < 2; ++in)
        bfr[in] = *(const bf16x8*)&Bs[(wave * 32 + in * 16 + lr) * 64 + pa * 8];

      #pragma unroll
      for (int im = 0; im < 4; ++im)
        #pragma unroll
        for (int in = 0; in < 2; ++in)
          acc[im][in] = __builtin_amdgcn_mfma_f32_16x16x32_bf16(
              af[im], bfr[in], acc[im][in], 0, 0, 0);
    }
    __syncthreads();
  }

  #pragma unroll
  for (int im = 0; im < 4; ++im) {
    const int mbase = m0 + im * 16 + lq * 4;
    #pragma unroll
    for (int in = 0; in < 2; ++in) {
      const int ncol = n0 + wave * 32 + in * 16 + lr;
      #pragma unroll
      for (int r = 0; r < 4; ++r) {
        const int m = mbase + r;
        store_out(C + (size_t)m * N + ncol, acc[im][in][r] + bias[m]);
      }
    }
  }
}

// ---------------------------------------------------------------------------
// Prep: P,I fp32->bf16 transposed + 3 weight casts + SCORE zeroing
// (proven R9). Champion 32x33 tile path. Grid 14352.
// ---------------------------------------------------------------------------
__global__ __launch_bounds__(256)
void prep(const float* __restrict__ P, u16* __restrict__ PT,
          const float* __restrict__ I, u16* __restrict__ IT,
          const float4* __restrict__ wim, const float4* __restrict__ wl,
          const float4* __restrict__ wf, ushort4* __restrict__ wimb,
          ushort4* __restrict__ wlb, ushort4* __restrict__ wfb,
          float* __restrict__ score)
{
  const int bid = blockIdx.x;
  if (bid < 8192) {
    const int z   = bid >> 12;          // 0: P, 1: I
    const int rem = bid & 4095;
    const int bx  = rem & 127;
    const int byy = rem >> 7;
    const float* in = z ? I : P;
    u16* out = z ? IT : PT;
    __shared__ u16 tile[32][33];
    const int c0 = bx * 32, r0 = byy * 32;
    const int tx = threadIdx.x & 31, ty = threadIdx.x >> 5;
    #pragma unroll
    for (int k = 0; k < 4; ++k)
      tile[ty + 8 * k][tx] = f2b(in[(size_t)(r0 + ty + 8 * k) * 4096 + c0 + tx]);
    __syncthreads();
    #pragma unroll
    for (int k = 0; k < 4; ++k)
      out[(size_t)(c0 + ty + 8 * k) * 1024 + r0 + tx] = tile[tx][ty + 8 * k];
  } else if (bid < 14336) {
    int i = (bid - 8192) * 256 + threadIdx.x;
    const float4* src; ushort4* dst;
    if (i < 1048576)      { src = wim; dst = wimb; }
    else if (i < 1310720) { src = wl;  dst = wlb;  i -= 1048576; }
    else                  { src = wf;  dst = wfb;  i -= 1310720; }
    const float4 v = src[i];
    ushort4 o;
    o.x = f2b(v.x); o.y = f2b(v.y); o.z = f2b(v.z); o.w = f2b(v.w);
    dst[i] = o;
  } else {
    // 16 blocks x 256 threads x 4 floats = 16384 = 4*4096 (SCORE zero)
    const int i = (bid - 14336) * 1024 + threadIdx.x * 4;
    *(float4*)&score[i] = (float4){0.f, 0.f, 0.f, 0.f};
  }
}

// bf16 [R x C] -> bf16 [C x R]  (champion 32x33)
__global__ __launch_bounds__(256)
void transpose_u16(const u16* __restrict__ in, u16* __restrict__ out,
                   int R, int C)
{
  __shared__ u16 tile[32][33];
  const int c0 = blockIdx.x * 32, r0 = blockIdx.y * 32;
  const int tx = threadIdx.x & 31, ty = threadIdx.x >> 5;
  #pragma unroll
  for (int k = 0; k < 4; ++k)
    tile[ty + 8 * k][tx] = in[(size_t)(r0 + ty + 8 * k) * C + c0 + tx];
  __syncthreads();
  #pragma unroll
  for (int k = 0; k < 4; ++k)
    out[(size_t)(c0 + ty + 8 * k) * R + r0 + tx] = tile[tx][ty + 8 * k];
}

// ---------------------------------------------------------------------------
// z_ln with INLINE softmax: reads SCORE (L2-hot, same bytes as the old wmap
// read), computes the 4-head softmax per element, uses it for z, and block 0
// writes the wmap output. Kills the softmax_h dispatch.
// ---------------------------------------------------------------------------
__global__ __launch_bounds__(256)
void z_ln(const u16* __restrict__ keys, const u16* __restrict__ Qb,
          const float* __restrict__ score, const float* __restrict__ g,
          const float* __restrict__ bb, u16* __restrict__ fused,
          float* __restrict__ wmap)
{
  const int c  = blockIdx.x;
  const int tx = threadIdx.x;
  float t[16];
  float s = 0.f, s2 = 0.f;
  #pragma unroll
  for (int j = 0; j < 2; ++j) {
    const int n = tx * 8 + j * 2048;

    // inline softmax over heads for these 8 n's
    float sc[4][8];
    #pragma unroll
    for (int h = 0; h < 4; ++h) {
      const float4 a = *(const float4*)&score[h * 4096 + n];
      const float4 b = *(const float4*)&score[h * 4096 + n + 4];
      sc[h][0] = a.x; sc[h][1] = a.y; sc[h][2] = a.z; sc[h][3] = a.w;
      sc[h][4] = b.x; sc[h][5] = b.y; sc[h][6] = b.z; sc[h][7] = b.w;
    }
    float wv[4][8];
    #pragma unroll
    for (int e = 0; e < 8; ++e) {
      const float m = fmaxf(fmaxf(sc[0][e], sc[1][e]),
                            fmaxf(sc[2][e], sc[3][e]));
      const float e0 = expf(sc[0][e] - m), e1 = expf(sc[1][e] - m);
      const float e2 = expf(sc[2][e] - m), e3 = expf(sc[3][e] - m);
      const float inv = 1.f / (e0 + e1 + e2 + e3);
      wv[0][e] = e0 * inv; wv[1][e] = e1 * inv;
      wv[2][e] = e2 * inv; wv[3][e] = e3 * inv;
    }
    if (c == 0) {
      #pragma unroll
      for (int h = 0; h < 4; ++h) {
        float4 o0 = {wv[h][0], wv[h][1], wv[h][2], wv[h][3]};
        float4 o1 = {wv[h][4], wv[h][5], wv[h][6], wv[h][7]};
        *(float4*)&wmap[h * 4096 + n]     = o0;
        *(float4*)&wmap[h * 4096 + n + 4] = o1;
      }
    }

    const uint4 qv = *(const uint4*)&Qb[(size_t)c * 4096 + n];
    float z[8] = {0.f,0.f,0.f,0.f,0.f,0.f,0.f,0.f};
    #pragma unroll
    for (int h = 0; h < 4; ++h) {
      const uint4 kv = *(const uint4*)&keys[((size_t)((h << 10) + c)) * 4096 + n];
      z[0] = fmaf(wv[h][0], b2f_lo(kv.x), z[0]);
      z[1] = fmaf(wv[h][1], b2f_hi(kv.x), z[1]);
      z[2] = fmaf(wv[h][2], b2f_lo(kv.y), z[2]);
      z[3] = fmaf(wv[h][3], b2f_hi(kv.y), z[3]);
      z[4] = fmaf(wv[h][4], b2f_lo(kv.z), z[4]);
      z[5] = fmaf(wv[h][5], b2f_hi(kv.z), z[5]);
      z[6] = fmaf(wv[h][6], b2f_lo(kv.w), z[6]);
      z[7] = fmaf(wv[h][7], b2f_hi(kv.w), z[7]);
    }
    const uint32_t qs[4] = {qv.x, qv.y, qv.z, qv.w};
    #pragma unroll
    for (int e = 0; e < 4; ++e) {
      const float v0 = z[2 * e]     + b2f_lo(qs[e]);
      const float v1 = z[2 * e + 1] + b2f_hi(qs[e]);
      t[8 * j + 2 * e]     = v0;
      t[8 * j + 2 * e + 1] = v1;
      s += v0 + v1;
      s2 = fmaf(v0, v0, fmaf(v1, v1, s2));
    }
  }
  #pragma unroll
  for (int o = 32; o > 0; o >>= 1) {
    s  += __shfl_down(s, o);
    s2 += __shfl_down(s2, o);
  }
  __shared__ float rbuf[8];
  const int wave = tx >> 6, lane = tx & 63;
  if (lane == 0) { rbuf[wave] = s; rbuf[4 + wave] = s2; }
  __syncthreads();
  s  = rbuf[0] + rbuf[1] + rbuf[2] + rbuf[3];
  s2 = rbuf[4] + rbuf[5] + rbuf[6] + rbuf[7];
  const float mu  = s * (1.f / 4096.f);
  const float var = s2 * (1.f / 4096.f) - mu * mu;
  const float rs  = rsqrtf(var + 1e-5f);
  #pragma unroll
  for (int j = 0; j < 2; ++j) {
    const int n = tx * 8 + j * 2048;
    #pragma unroll
    for (int q4 = 0; q4 < 2; ++q4) {
      const float4 gv = *(const float4*)&g[n + 4 * q4];
      const float4 bv = *(const float4*)&bb[n + 4 * q4];
      ushort4 o;
      o.x = f2b((t[8 * j + 4 * q4]     - mu) * rs * gv.x + bv.x);
      o.y = f2b((t[8 * j + 4 * q4 + 1] - mu) * rs * gv.y + bv.y);
      o.z = f2b((t[8 * j + 4 * q4 + 2] - mu) * rs * gv.z + bv.z);
      o.w = f2b((t[8 * j + 4 * q4 + 3] - mu) * rs * gv.w + bv.w);
      *(ushort4*)&fused[(size_t)c * 4096 + n + 4 * q4] = o;
    }
  }
}

extern "C" void kernel_launch(void* const* d_in, const int* in_sizes, int n_in,
                              void* d_out, int out_size, void* d_ws, size_t ws_size,
                              hipStream_t stream)
{
  const float* P   = (const float*)d_in[0];
  const float* I   = (const float*)d_in[1];
  const float* Wim = (const float*)d_in[2];
  const float* bim = (const float*)d_in[3];
  const float* WL  = (const float*)d_in[4];
  const float* bL  = (const float*)d_in[5];
  const float* lng = (const float*)d_in[6];
  const float* lnb = (const float*)d_in[7];
  const float* Wf  = (const float*)d_in[8];
  const float* bf_ = (const float*)d_in[9];
  float* out = (float*)d_out;

  char* ws = (char*)d_ws;
  u16*   PT     = (u16*)(ws + 0);                      //  8 MB [4096 x 1024]
  u16*   IT     = (u16*)(ws + (size_t)8  * 1048576);   //  8 MB
  u16*   WLb    = (u16*)(ws + (size_t)16 * 1048576);   //  2 MB
  u16*   WIb    = (u16*)(ws + (size_t)18 * 1048576);   //  8 MB
  u16*   WFb    = (u16*)(ws + (size_t)26 * 1048576);   //  2 MB
  u16*   Qb     = (u16*)(ws + (size_t)28 * 1048576);   //  8 MB [1024 x 4096]
  u16*   KEYS   = (u16*)(ws + (size_t)36 * 1048576);   // 32 MB [4096 x 4096]
  float* SCORE  = (float*)(ws + (size_t)68 * 1048576); // 64 KB [4 x 4096]
  u16*   FUSED  = (u16*)(ws + (size_t)70 * 1048576);   //  8 MB [1024 x 4096]
  u16*   FUSEDT = (u16*)(ws + (size_t)78 * 1048576);   //  8 MB [4096 x 1024]

  const dim3 b256(256);

  // input casts/transposes + SCORE zeroing, one dispatch (14352 blocks)
  prep<<<14352, b256, 0, stream>>>(P, PT, I, IT,
                                   (const float4*)Wim, (const float4*)WL,
                                   (const float4*)Wf, (ushort4*)WIb,
                                   (ushort4*)WLb, (ushort4*)WFb, SCORE);

  // Q = W_L * P^T  [1024 x 4096] bf16 (512 blocks, 2/CU)
  gemm_bt_64<u16><<<dim3(32, 16), b256, 0, stream>>>(WLb, PT, bL, Qb,
                                                     1024, 4096, 1024);

  // keys [4096x4096] bf16 with FUSED score accumulation (1024 blocks)
  gemm_keys_score<<<dim3(32, 32), b256, 0, stream>>>(WIb, IT, bim, KEYS,
                                                     Qb, SCORE);

  // z + residual + LayerNorm (inline softmax; block 0 writes wmap)
  float* wmap = out + (size_t)1024 * 4096;
  z_ln<<<1024, b256, 0, stream>>>(KEYS, Qb, SCORE, lng, lnb, FUSED, wmap);
  transpose_u16<<<dim3(128, 32), b256, 0, stream>>>(FUSED, FUSEDT, 1024, 4096);

  // out = W_f * fused + b_f  [1024 x 4096] fp32
  gemm_bt_64<float><<<dim3(32, 16), b256, 0, stream>>>(WFb, FUSEDT, bf_, out,
                                                       1024, 4096, 1024);
}